// Round 8
// baseline (635.490 us; speedup 1.0000x reference)
//
#include <hip/hip_runtime.h>
#include <hip/hip_bf16.h>

typedef _Float16 f16;
typedef __attribute__((ext_vector_type(8))) _Float16 f16x8;
typedef __attribute__((ext_vector_type(4))) _Float16 f16x4;
typedef __attribute__((ext_vector_type(2))) _Float16 f16x2;
typedef __attribute__((ext_vector_type(4))) float floatx4;

// Problem constants
constexpr int B  = 8;
constexpr int N  = 2048;
constexpr int Fv = 3;
constexpr int Dd = 256;
constexpr int QK = 512;
constexpr int Vd = 512;
constexpr int Hh = 8;
constexpr int Qq = 64;
constexpr int DH = 64;
constexpr int NT = B * N;          // 16384 tokens
constexpr float EPS = 1e-6f;
constexpr float NEG = 0.2f;
constexpr float LNE = 1e-6f;

#define DEV static __device__ __forceinline__
DEV void split(float v, f16& h, f16& l) { h = (f16)v; l = (f16)(v - (float)h); }

// ---------------------------------------------------------------------------
// Split-fp16 3-mul GEMM (effective fp32 accuracy): C = A[M,K] @ B[K,N]
// A as (Ah,Al) f16 pairs (ASRC=0) or fp32 split on the fly (ASRC=1).
// Bt = B^T row-major [N,K] as (Bh,Bl) pairs.
// Block 256 thr = 4 waves; tile 128M x 64N; wave = 32 rows x 64 cols.
// EPI: 0 pair store                 1 +bias,leaky -> pair
//      2 +bias -> f32               3 per-64col LN -> f16 pair [h][tok][64]
//      5 PV2: store f32 resiT[(b,q,f)][512] at col h*64+
// ---------------------------------------------------------------------------
template<int ASRC, int EPI>
__global__ __launch_bounds__(256) void k_gemm3(
    const float* __restrict__ A32,
    const f16* __restrict__ Ah, const f16* __restrict__ Al,
    const f16* __restrict__ Bh, const f16* __restrict__ Bl,
    int Ndim, int Kdim, void* __restrict__ C1, void* __restrict__ C2,
    const float* __restrict__ e0, const float* __restrict__ e1)
{
    __shared__ __align__(16) f16 Ash[128][72];
    __shared__ __align__(16) f16 Asl[128][72];
    __shared__ __align__(16) f16 Bsh[64][72];
    __shared__ __align__(16) f16 Bsl[64][72];

    const int t = threadIdx.x;
    long row0; int col0, boff;
    if (EPI == 5) { row0 = (long)blockIdx.y * 1536 + (long)blockIdx.x * 128; col0 = 0; boff = blockIdx.y * 64; }
    else          { row0 = (long)blockIdx.x * 128; col0 = blockIdx.y * 64; boff = 0; }

    floatx4 acc0[4], acc1[4];
    #pragma unroll
    for (int nt = 0; nt < 4; ++nt)
        #pragma unroll
        for (int j = 0; j < 4; ++j) { acc0[nt][j] = 0.f; acc1[nt][j] = 0.f; }

    const int L = t & 63, w = t >> 6;
    const int kq = (L >> 4) << 3;

    for (int k0 = 0; k0 < Kdim; k0 += 64) {
        if constexpr (ASRC == 1) {
            #pragma unroll
            for (int j = 0; j < 8; ++j) {
                const int i = t + j * 256;
                const int r = i >> 4, c4 = (i & 15) << 2;
                const floatx4 v = *(const floatx4*)&A32[(row0 + r) * Kdim + k0 + c4];
                f16x4 h4, l4;
                #pragma unroll
                for (int m = 0; m < 4; ++m) { h4[m] = (f16)v[m]; l4[m] = (f16)(v[m] - (float)h4[m]); }
                *(f16x4*)&Ash[r][c4] = h4;
                *(f16x4*)&Asl[r][c4] = l4;
            }
        } else {
            #pragma unroll
            for (int j = 0; j < 4; ++j) {
                const int i = t + j * 256;
                const int r = i >> 3, c8 = (i & 7) << 3;
                *(f16x8*)&Ash[r][c8] = *(const f16x8*)&Ah[(row0 + r) * (long)Kdim + k0 + c8];
                *(f16x8*)&Asl[r][c8] = *(const f16x8*)&Al[(row0 + r) * (long)Kdim + k0 + c8];
            }
        }
        #pragma unroll
        for (int j = 0; j < 2; ++j) {
            const int i = t + j * 256;
            const int r = i >> 3, c8 = (i & 7) << 3;
            *(f16x8*)&Bsh[r][c8] = *(const f16x8*)&Bh[(long)(boff + col0 + r) * Kdim + k0 + c8];
            *(f16x8*)&Bsl[r][c8] = *(const f16x8*)&Bl[(long)(boff + col0 + r) * Kdim + k0 + c8];
        }
        __syncthreads();
        #pragma unroll
        for (int kk = 0; kk < 64; kk += 32) {
            const f16x8 ah0 = *(const f16x8*)&Ash[w * 32 + (L & 15)][kk + kq];
            const f16x8 al0 = *(const f16x8*)&Asl[w * 32 + (L & 15)][kk + kq];
            const f16x8 ah1 = *(const f16x8*)&Ash[w * 32 + 16 + (L & 15)][kk + kq];
            const f16x8 al1 = *(const f16x8*)&Asl[w * 32 + 16 + (L & 15)][kk + kq];
            #pragma unroll
            for (int nt = 0; nt < 4; ++nt) {
                const f16x8 bh = *(const f16x8*)&Bsh[nt * 16 + (L & 15)][kk + kq];
                const f16x8 bl = *(const f16x8*)&Bsl[nt * 16 + (L & 15)][kk + kq];
                acc0[nt] = __builtin_amdgcn_mfma_f32_16x16x32_f16(ah0, bh, acc0[nt], 0, 0, 0);
                acc0[nt] = __builtin_amdgcn_mfma_f32_16x16x32_f16(ah0, bl, acc0[nt], 0, 0, 0);
                acc0[nt] = __builtin_amdgcn_mfma_f32_16x16x32_f16(al0, bh, acc0[nt], 0, 0, 0);
                acc1[nt] = __builtin_amdgcn_mfma_f32_16x16x32_f16(ah1, bh, acc1[nt], 0, 0, 0);
                acc1[nt] = __builtin_amdgcn_mfma_f32_16x16x32_f16(ah1, bl, acc1[nt], 0, 0, 0);
                acc1[nt] = __builtin_amdgcn_mfma_f32_16x16x32_f16(al1, bh, acc1[nt], 0, 0, 0);
            }
        }
        __syncthreads();
    }

    // C/D layout: col = lane&15, row = (lane>>4)*4 + reg
    const int cb = L & 15;
    #pragma unroll
    for (int rt = 0; rt < 2; ++rt) {
        const floatx4* acc = rt ? acc1 : acc0;
        const int rb = w * 32 + rt * 16 + ((L >> 4) << 2);
        if constexpr (EPI == 0) {
            f16* Ch = (f16*)C1; f16* Cl = (f16*)C2;
            #pragma unroll
            for (int nt = 0; nt < 4; ++nt)
                #pragma unroll
                for (int r = 0; r < 4; ++r) {
                    f16 h, l; split(acc[nt][r], h, l);
                    const long o = (row0 + rb + r) * (long)Ndim + col0 + nt * 16 + cb;
                    Ch[o] = h; Cl[o] = l;
                }
        } else if constexpr (EPI == 1) {
            f16* Ch = (f16*)C1; f16* Cl = (f16*)C2;
            #pragma unroll
            for (int nt = 0; nt < 4; ++nt) {
                const int col = col0 + nt * 16 + cb;
                const float bias = e0[col];
                #pragma unroll
                for (int r = 0; r < 4; ++r) {
                    float v = acc[nt][r] + bias;
                    v = v > 0.f ? v : NEG * v;
                    f16 h, l; split(v, h, l);
                    const long o = (row0 + rb + r) * (long)Ndim + col;
                    Ch[o] = h; Cl[o] = l;
                }
            }
        } else if constexpr (EPI == 2) {
            float* C = (float*)C1;
            #pragma unroll
            for (int nt = 0; nt < 4; ++nt) {
                const int col = col0 + nt * 16 + cb;
                const float bias = e0[col];
                #pragma unroll
                for (int r = 0; r < 4; ++r)
                    C[(row0 + rb + r) * (long)Ndim + col] = acc[nt][r] + bias;
            }
        } else if constexpr (EPI == 3) {
            f16* Ch = (f16*)C1; f16* Cl = (f16*)C2;
            const int h = blockIdx.y;
            #pragma unroll
            for (int r = 0; r < 4; ++r) {
                float s = 0.f, q = 0.f;
                #pragma unroll
                for (int nt = 0; nt < 4; ++nt) { const float v = acc[nt][r]; s += v; q += v * v; }
                s += __shfl_xor(s, 1); q += __shfl_xor(q, 1);
                s += __shfl_xor(s, 2); q += __shfl_xor(q, 2);
                s += __shfl_xor(s, 4); q += __shfl_xor(q, 4);
                s += __shfl_xor(s, 8); q += __shfl_xor(q, 8);
                const float mean = s * (1.f / 64.f);
                const float var  = q * (1.f / 64.f) - mean * mean;
                const float rs   = rsqrtf(var + LNE);
                #pragma unroll
                for (int nt = 0; nt < 4; ++nt) {
                    const int col = nt * 16 + cb;
                    const float v = (acc[nt][r] - mean) * rs * e0[col] + e1[col];
                    f16 hh, ll; split(v, hh, ll);
                    const long o = ((long)h * NT + row0 + rb + r) * 64 + col;
                    Ch[o] = hh; Cl[o] = ll;
                }
            }
        } else {  // EPI == 5
            float* C = (float*)C1;
            #pragma unroll
            for (int nt = 0; nt < 4; ++nt)
                #pragma unroll
                for (int r = 0; r < 4; ++r) {
                    const long rr = row0 + rb + r - (long)blockIdx.y * 1536;
                    C[rr * 512 + boff + nt * 16 + cb] = acc[nt][r];
                }
        }
    }
}

// ---------------------------------------------------------------------------
// Round-7: barrier-free register-streaming GEMM for kv_pre = x @ w_kv.
// K=256 made the LDS-staged k_gemm3 latency/barrier-bound (4 K-iters, 2
// barriers each, fp32->f16 split VALU between barriers, 2 blocks/CU).
// Here: each wave owns 32 rows x full K=256. The MFMA A-fragment layout
// (row=L&15, k=(L>>4)*8..) is DIRECTLY loadable from global as coalesced
// 32B/lane strips -> A loaded once into 128 VGPRs of f16 pairs (split done
// in-register, no LDS round-trip). B (w_kv pair, 512KB) is L2-resident ->
// fragments read straight from L2 per col-chunk. Zero LDS, zero barriers.
// Grid 768 x 128thr = 2 waves/block = exactly 3 blocks/CU (6 waves, VGPR-
// bound ~195). B L2 traffic 786MB ~ 23us at L2 BW, hidden under MFMA.
// ---------------------------------------------------------------------------
__global__ __launch_bounds__(128, 2) void k_kvstream(
    const float* __restrict__ x,
    const f16* __restrict__ Bh, const f16* __restrict__ Bl,
    f16* __restrict__ Ch, f16* __restrict__ Cl)
{
    const int t = threadIdx.x;
    const int L = t & 63, w = t >> 6;          // 2 waves/block
    const long wid = (long)blockIdx.x * 2 + w; // 0..1535
    const long row0 = wid * 32;

    const int arow = L & 15;       // row within 16-row group
    const int akg = L >> 4;        // k-subgroup (8 elems each)
    const int cb = L & 15;

    // ---- A: 32 rows x 256 K -> registers as f16 pairs (one-time) ----
    f16x8 axh[2][8], axl[2][8];
    #pragma unroll
    for (int rg = 0; rg < 2; ++rg) {
        const float* ap = x + (row0 + rg * 16 + arow) * 256 + akg * 8;
        #pragma unroll
        for (int ks = 0; ks < 8; ++ks) {
            const floatx4 v0 = *(const floatx4*)&ap[ks * 32];
            const floatx4 v1 = *(const floatx4*)&ap[ks * 32 + 4];
            f16x8 h8, l8;
            #pragma unroll
            for (int m = 0; m < 4; ++m) {
                f16 hh, ll;
                split(v0[m], hh, ll); h8[m] = hh;     l8[m] = ll;
                split(v1[m], hh, ll); h8[m + 4] = hh; l8[m + 4] = ll;
            }
            axh[rg][ks] = h8; axl[rg][ks] = l8;
        }
    }

    // ---- sweep 8 col-chunks of 64; B fragments straight from L2 ----
    for (int ct = 0; ct < 8; ++ct) {
        floatx4 acc[2][4];
        #pragma unroll
        for (int rg = 0; rg < 2; ++rg)
            #pragma unroll
            for (int nt = 0; nt < 4; ++nt)
                #pragma unroll
                for (int j = 0; j < 4; ++j) acc[rg][nt][j] = 0.f;

        #pragma unroll
        for (int ks = 0; ks < 8; ++ks) {
            #pragma unroll
            for (int nt = 0; nt < 4; ++nt) {
                const long bo = (long)(ct * 64 + nt * 16 + cb) * 256 + ks * 32 + akg * 8;
                const f16x8 bh = *(const f16x8*)&Bh[bo];
                const f16x8 bl = *(const f16x8*)&Bl[bo];
                acc[0][nt] = __builtin_amdgcn_mfma_f32_16x16x32_f16(axh[0][ks], bh, acc[0][nt], 0, 0, 0);
                acc[0][nt] = __builtin_amdgcn_mfma_f32_16x16x32_f16(axh[0][ks], bl, acc[0][nt], 0, 0, 0);
                acc[0][nt] = __builtin_amdgcn_mfma_f32_16x16x32_f16(axl[0][ks], bh, acc[0][nt], 0, 0, 0);
                acc[1][nt] = __builtin_amdgcn_mfma_f32_16x16x32_f16(axh[1][ks], bh, acc[1][nt], 0, 0, 0);
                acc[1][nt] = __builtin_amdgcn_mfma_f32_16x16x32_f16(axh[1][ks], bl, acc[1][nt], 0, 0, 0);
                acc[1][nt] = __builtin_amdgcn_mfma_f32_16x16x32_f16(axl[1][ks], bh, acc[1][nt], 0, 0, 0);
            }
        }

        // epilogue: C/D layout col=lane&15, row=(lane>>4)*4+reg
        #pragma unroll
        for (int rg = 0; rg < 2; ++rg) {
            const int rb = rg * 16 + ((L >> 4) << 2);
            #pragma unroll
            for (int nt = 0; nt < 4; ++nt)
                #pragma unroll
                for (int r = 0; r < 4; ++r) {
                    f16 h, l; split(acc[rg][nt][r], h, l);
                    const long o = (row0 + rb + r) * 512 + ct * 64 + nt * 16 + cb;
                    Ch[o] = h; Cl[o] = l;
                }
        }
    }
}

// ---------------------------------------------------------------------------
// Attention scores via MFMA. Grid 512 = 64 hb x 8 n-parts (2/CU).
// Each block does 4 K-tiles of a 256-token slice; partial row-sums go to
// lsum_part[part][hb*64+q], reduced by k_lsum_reduce.
// S[q,n] = (qv . k)/8 ; p = exp(S) (no max-sub: |S|<=8 after LN).
// ---------------------------------------------------------------------------
__global__ __launch_bounds__(256) void k_attn_mfma(
    const f16* __restrict__ qh, const f16* __restrict__ ql,
    const f16* __restrict__ kh, const f16* __restrict__ kl,
    f16* __restrict__ ath, f16* __restrict__ atl, float* __restrict__ lsum_part)
{
    __shared__ __align__(16) f16 Qh[64][72], Ql[64][72];
    __shared__ __align__(16) f16 Kh[64][72], Kl[64][72];

    const int t = threadIdx.x;
    const int bx = blockIdx.x;
    const int hb = bx & 63;
    const int part = bx >> 6;        // 0..7
    const int h = hb >> 3;
    const int L = t & 63, w = t >> 6;
    const int kq = (L >> 4) << 3;

    #pragma unroll
    for (int j = 0; j < 2; ++j) {
        const int i = t + j * 256;
        const int r = i >> 3, c8 = (i & 7) << 3;
        *(f16x8*)&Qh[r][c8] = *(const f16x8*)&qh[((long)h * 64 + r) * 64 + c8];
        *(f16x8*)&Ql[r][c8] = *(const f16x8*)&ql[((long)h * 64 + r) * 64 + c8];
    }
    __syncthreads();

    f16x8 qah[2], qal[2];
    #pragma unroll
    for (int kc = 0; kc < 2; ++kc) {
        qah[kc] = *(const f16x8*)&Qh[w * 16 + (L & 15)][kc * 32 + kq];
        qal[kc] = *(const f16x8*)&Ql[w * 16 + (L & 15)][kc * 32 + kq];
    }

    float psum[4] = {0.f, 0.f, 0.f, 0.f};
    const int rowb = w * 16 + ((L >> 4) << 2);

    for (int nt0 = 0; nt0 < 4; ++nt0) {
        const int n0 = part * 256 + nt0 * 64;
        __syncthreads();
        #pragma unroll
        for (int j = 0; j < 2; ++j) {
            const int i = t + j * 256;
            const int r = i >> 3, c8 = (i & 7) << 3;
            *(f16x8*)&Kh[r][c8] = *(const f16x8*)&kh[((long)hb * N + n0 + r) * 64 + c8];
            *(f16x8*)&Kl[r][c8] = *(const f16x8*)&kl[((long)hb * N + n0 + r) * 64 + c8];
        }
        __syncthreads();

        floatx4 acc[4];
        #pragma unroll
        for (int nt = 0; nt < 4; ++nt)
            #pragma unroll
            for (int j = 0; j < 4; ++j) acc[nt][j] = 0.f;

        #pragma unroll
        for (int kc = 0; kc < 2; ++kc) {
            #pragma unroll
            for (int nt = 0; nt < 4; ++nt) {
                const f16x8 bh = *(const f16x8*)&Kh[nt * 16 + (L & 15)][kc * 32 + kq];
                const f16x8 bl = *(const f16x8*)&Kl[nt * 16 + (L & 15)][kc * 32 + kq];
                acc[nt] = __builtin_amdgcn_mfma_f32_16x16x32_f16(qah[kc], bh, acc[nt], 0, 0, 0);
                acc[nt] = __builtin_amdgcn_mfma_f32_16x16x32_f16(qah[kc], bl, acc[nt], 0, 0, 0);
                acc[nt] = __builtin_amdgcn_mfma_f32_16x16x32_f16(qal[kc], bh, acc[nt], 0, 0, 0);
            }
        }

        #pragma unroll
        for (int nt = 0; nt < 4; ++nt)
            #pragma unroll
            for (int r = 0; r < 4; ++r) {
                const float p = __expf(acc[nt][r] * 0.125f);
                psum[r] += p;
                f16 hh, ll; split(p, hh, ll);
                const long o = ((long)hb * 64 + rowb + r) * N + n0 + nt * 16 + (L & 15);
                ath[o] = hh; atl[o] = ll;
            }
    }

    #pragma unroll
    for (int r = 0; r < 4; ++r) {
        float s = psum[r];
        s += __shfl_xor(s, 1);
        s += __shfl_xor(s, 2);
        s += __shfl_xor(s, 4);
        s += __shfl_xor(s, 8);
        if ((L & 15) == 0) lsum_part[part * 4096 + hb * 64 + rowb + r] = s;
    }
}

// lsum[i] = sum_p lsum_part[p][i] (deterministic, 16 blocks x 256)
__global__ void k_lsum_reduce(const float* __restrict__ part, float* __restrict__ lsum)
{
    const int i = blockIdx.x * 256 + threadIdx.x;
    float s = 0.f;
    #pragma unroll
    for (int p = 0; p < 8; ++p) s += part[p * 4096 + i];
    lsum[i] = s;
}

// ---------------------------------------------------------------------------
// PV1: U[hb*64+q, fd] = (1/lsum[row]) * sum_n p[row,n] * kv[b][n, fd]
// Dist-2 register pipeline (round-6 WIN): WRITE consumes regs loaded a full
// iteration earlier -> dependency-driven counted vmcnt. Swizzled LDS
// (round-5) keeps reads conflict-free. Dbuf BK=32, 1 barrier/tile;
// LDS 56 KB; 2 blocks/CU; wave 32x48.
// ---------------------------------------------------------------------------
__global__ __launch_bounds__(512, 4) void k_gemm3T(
    const f16* __restrict__ Ah, const f16* __restrict__ Al,
    const f16* __restrict__ Bh, const f16* __restrict__ Bl,
    const float* __restrict__ lsum,
    f16* __restrict__ Uh, f16* __restrict__ Ul)
{
    __shared__ __align__(16) f16 Ash[2][128][32];
    __shared__ __align__(16) f16 Asl[2][128][32];
    __shared__ __align__(16) f16 Bsh[2][96][32];
    __shared__ __align__(16) f16 Bsl[2][96][32];

    const int t = threadIdx.x;
    const int by = blockIdx.x;
    const int b = by & 7;
    const int rest = by >> 3;        // 0..63
    const int ct = rest & 15;        // 96-col chunk
    const int hp = rest >> 4;        // 0..3
    const int hb0 = b + 16 * hp;
    const int hb1 = hb0 + 8;

    // A staging: thread -> (row ar, granule t&3); swizzled granule constant
    const int ar = t >> 2;                                // 0..127
    const int apg = (((t & 3) ^ ((t >> 3) & 3)) << 3);    // phys halfword off
    const f16* Arh = (ar < 64)
        ? Ah + ((long)hb0 * 64 + ar) * 2048
        : Ah + ((long)hb1 * 64 + (ar - 64)) * 2048;
    const f16* Arl = (ar < 64)
        ? Al + ((long)hb0 * 64 + ar) * 2048
        : Al + ((long)hb1 * 64 + (ar - 64)) * 2048;
    const int aseg = (t & 3) << 3;       // logical k-offset in global

    // B staging (transpose): threads 0..191, each 2 k-rows x 8 cols
    const f16* Bbh = Bh + (long)b * 2048 * 1536 + ct * 96;
    const f16* Bbl = Bl + (long)b * 2048 * 1536 + ct * 96;
    const bool bstage = t < 192;
    const int k2 = t & 15;               // k-pair 0..15
    const int cg = t >> 4;               // col group 0..11 (valid for t<192)

    floatx4 acc[2][3];
    #pragma unroll
    for (int i = 0; i < 2; ++i)
        #pragma unroll
        for (int nt = 0; nt < 3; ++nt)
            #pragma unroll
            for (int j = 0; j < 4; ++j) acc[i][nt][j] = 0.f;

    const int L = t & 63, w = t >> 6;
    const int wr = (w >> 1) << 5;        // 0,32,64,96
    const int wc = (w & 1) * 48;         // 0,48
    // swizzled fragment-read column: logical granule L>>4, row-XOR (L>>1)&3
    const int kqs = (((L >> 4) ^ ((L >> 1) & 3)) << 3);

    // two named staging-register sets (static roles, unroll x2)
    f16x8 pAh, pAl, pB0h, pB1h, pB0l, pB1l;   // set RA
    f16x8 qAh, qAl, qB0h, qB1h, qB0l, qB1l;   // set RB

    auto LOADA = [&](int k0) {
        pAh = *(const f16x8*)&Arh[k0 + aseg];
        pAl = *(const f16x8*)&Arl[k0 + aseg];
        if (bstage) {
            const long r0 = (long)(k0 + 2 * k2) * 1536 + cg * 8;
            pB0h = *(const f16x8*)&Bbh[r0];
            pB1h = *(const f16x8*)&Bbh[r0 + 1536];
            pB0l = *(const f16x8*)&Bbl[r0];
            pB1l = *(const f16x8*)&Bbl[r0 + 1536];
        }
    };
    auto LOADB = [&](int k0) {
        qAh = *(const f16x8*)&Arh[k0 + aseg];
        qAl = *(const f16x8*)&Arl[k0 + aseg];
        if (bstage) {
            const long r0 = (long)(k0 + 2 * k2) * 1536 + cg * 8;
            qB0h = *(const f16x8*)&Bbh[r0];
            qB1h = *(const f16x8*)&Bbh[r0 + 1536];
            qB0l = *(const f16x8*)&Bbl[r0];
            qB1l = *(const f16x8*)&Bbl[r0 + 1536];
        }
    };
    auto WRITEA = [&](int buf) {
        *(f16x8*)&Ash[buf][ar][apg] = pAh;
        *(f16x8*)&Asl[buf][ar][apg] = pAl;
        if (bstage) {
            #pragma unroll
            for (int j = 0; j < 8; ++j) {
                const int hw = ((((k2 >> 2) ^ ((j >> 1) & 3)) << 3) | ((k2 & 3) << 1));
                f16x2 ph; ph[0] = pB0h[j]; ph[1] = pB1h[j];
                f16x2 pl; pl[0] = pB0l[j]; pl[1] = pB1l[j];
                *(f16x2*)&Bsh[buf][cg * 8 + j][hw] = ph;
                *(f16x2*)&Bsl[buf][cg * 8 + j][hw] = pl;
            }
        }
    };
    auto WRITEB = [&](int buf) {
        *(f16x8*)&Ash[buf][ar][apg] = qAh;
        *(f16x8*)&Asl[buf][ar][apg] = qAl;
        if (bstage) {
            #pragma unroll
            for (int j = 0; j < 8; ++j) {
                const int hw = ((((k2 >> 2) ^ ((j >> 1) & 3)) << 3) | ((k2 & 3) << 1));
                f16x2 ph; ph[0] = qB0h[j]; ph[1] = qB1h[j];
                f16x2 pl; pl[0] = qB0l[j]; pl[1] = qB1l[j];
                *(f16x2*)&Bsh[buf][cg * 8 + j][hw] = ph;
                *(f16x2*)&Bsl[buf][cg * 8 + j][hw] = pl;
            }
        }
    };
    auto COMPUTE = [&](int buf) {
        const f16x8 ah0 = *(const f16x8*)&Ash[buf][wr + (L & 15)][kqs];
        const f16x8 al0 = *(const f16x8*)&Asl[buf][wr + (L & 15)][kqs];
        const f16x8 ah1 = *(const f16x8*)&Ash[buf][wr + 16 + (L & 15)][kqs];
        const f16x8 al1 = *(const f16x8*)&Asl[buf][wr + 16 + (L & 15)][kqs];
        #pragma unroll
        for (int nt = 0; nt < 3; ++nt) {
            const f16x8 bh = *(const f16x8*)&Bsh[buf][wc + nt * 16 + (L & 15)][kqs];
            const f16x8 bl = *(const f16x8*)&Bsl[buf][wc + nt * 16 + (L & 15)][kqs];
            acc[0][nt] = __builtin_amdgcn_mfma_f32_16x16x32_f16(ah0, bh, acc[0][nt], 0, 0, 0);
            acc[0][nt] = __builtin_amdgcn_mfma_f32_16x16x32_f16(ah0, bl, acc[0][nt], 0, 0, 0);
            acc[0][nt] = __builtin_amdgcn_mfma_f32_16x16x32_f16(al0, bh, acc[0][nt], 0, 0, 0);
            acc[1][nt] = __builtin_amdgcn_mfma_f32_16x16x32_f16(ah1, bh, acc[1][nt], 0, 0, 0);
            acc[1][nt] = __builtin_amdgcn_mfma_f32_16x16x32_f16(ah1, bl, acc[1][nt], 0, 0, 0);
            acc[1][nt] = __builtin_amdgcn_mfma_f32_16x16x32_f16(al1, bh, acc[1][nt], 0, 0, 0);
        }
    };

    // prologue: tile0 -> buf0 (via RA), then preload tile1 into RA
    LOADA(0);
    WRITEA(0);
    LOADA(32);
    __syncthreads();
    // invariant at loop top (even tt): buf[tt&1] holds tile tt, RA holds tile tt+1

    for (int tt = 0; tt < 64; tt += 2) {
        // even half: compute tile tt (buf0), write tile tt+1 (RA) -> buf1
        if (tt + 2 < 64) LOADB((tt + 2) * 32);   // tile tt+2 -> RB (stays in flight)
        COMPUTE(0);
        if (tt + 1 < 64) WRITEA(1);              // waits only RA's loads (1 iter old)
        __syncthreads();
        // odd half: compute tile tt+1 (buf1), write tile tt+2 (RB) -> buf0
        if (tt + 3 < 64) LOADA((tt + 3) * 32);   // tile tt+3 -> RA
        COMPUTE(1);
        if (tt + 2 < 64) WRITEB(0);              // waits only RB's loads
        __syncthreads();
    }

    const int cb = L & 15;
    #pragma unroll
    for (int rt = 0; rt < 2; ++rt) {
        const int rloc = wr + rt * 16 + ((L >> 4) << 2);
        const int hb = (rloc < 64) ? hb0 : hb1;   // wave-uniform
        #pragma unroll
        for (int r = 0; r < 4; ++r) {
            const int q = (rloc + r) & 63;
            const float inv = 1.f / lsum[hb * 64 + q];
            #pragma unroll
            for (int nt = 0; nt < 3; ++nt) {
                f16 h, l; split(acc[rt][nt][r] * inv, h, l);
                const long o = ((long)hb * 64 + q) * 1536 + ct * 96 + wc + nt * 16 + cb;
                Uh[o] = h; Ul[o] = l;
            }
        }
    }
}

// ---------------------------------------------------------------------------
// f32 [K,N] -> transposed f16 pair [N,K]
__global__ void k_castTpair(const float* __restrict__ s, f16* __restrict__ dh,
                            f16* __restrict__ dl, int K, int Nn)
{
    const long i = (long)blockIdx.x * 256 + threadIdx.x;
    if (i >= (long)K * Nn) return;
    const int k = (int)(i / Nn), n = (int)(i - (long)k * Nn);
    f16 h, l; split(s[i], h, l);
    dh[(long)n * K + k] = h;
    dl[(long)n * K + k] = l;
}

// normb pair = f16pair( sqrt(sum_f pre^2) + EPS ).  Layout [tok*1536 + f*512 + c]
// (works for both kv_pre [NT toks] and resi_p [512 toks]).
__global__ void k_norm(const f16* __restrict__ kh, const f16* __restrict__ kl,
                       f16* __restrict__ nh, f16* __restrict__ nl)
{
    const long i = (long)blockIdx.x * 256 + threadIdx.x;
    const int tk = (int)(i >> 9), c = (int)(i & 511);
    const long base = (long)tk * 1536 + c;
    const float a = (float)kh[base]        + (float)kl[base];
    const float b = (float)kh[base + 512]  + (float)kl[base + 512];
    const float cc = (float)kh[base + 1024] + (float)kl[base + 1024];
    f16 h, l; split(sqrtf(a * a + b * b + cc * cc) + EPS, h, l);
    nh[i] = h; nl[i] = l;
}

// gate (in-place on kv pair) + kinv pair. One block per token.
__global__ __launch_bounds__(256) void k_gate(
    f16* __restrict__ kh, f16* __restrict__ kl, const float* __restrict__ g,
    f16* __restrict__ kih, f16* __restrict__ kil)
{
    __shared__ float red[3][4];
    const int t = threadIdx.x;
    const int tk = blockIdx.x;
    float kv[2][3];
    float ps0 = 0.f, ps1 = 0.f, ps2 = 0.f;
    #pragma unroll
    for (int j = 0; j < 2; ++j) {
        const int c = t + j * 256;
        const long base = (long)tk * 1536 + c;
        const float k0 = (float)kh[base]        + (float)kl[base];
        const float k1 = (float)kh[base + 512]  + (float)kl[base + 512];
        const float k2 = (float)kh[base + 1024] + (float)kl[base + 1024];
        const float nr = sqrtf(k0 * k0 + k1 * k1 + k2 * k2);
        const float gv = g[(long)tk * 512 + c];
        const float s = (nr <= EPS) ? 1.f : gv / (nr + EPS);
        kv[j][0] = k0 * s; kv[j][1] = k1 * s; kv[j][2] = k2 * s;
        f16 h, l;
        split(kv[j][0], h, l); kh[base] = h;        kl[base] = l;
        split(kv[j][1], h, l); kh[base + 512] = h;  kl[base + 512] = l;
        split(kv[j][2], h, l); kh[base + 1024] = h; kl[base + 1024] = l;
        ps0 += kv[j][0]; ps1 += kv[j][1]; ps2 += kv[j][2];
    }
    for (int off = 32; off; off >>= 1) {
        ps0 += __shfl_down(ps0, off);
        ps1 += __shfl_down(ps1, off);
        ps2 += __shfl_down(ps2, off);
    }
    if ((t & 63) == 0) { red[0][t >> 6] = ps0; red[1][t >> 6] = ps1; red[2][t >> 6] = ps2; }
    __syncthreads();
    const float m0 = (red[0][0] + red[0][1] + red[0][2] + red[0][3]) * (1.f / 512.f);
    const float m1 = (red[1][0] + red[1][1] + red[1][2] + red[1][3]) * (1.f / 512.f);
    const float m2 = (red[2][0] + red[2][1] + red[2][2] + red[2][3]) * (1.f / 512.f);
    #pragma unroll
    for (int j = 0; j < 2; ++j) {
        const int c = t + j * 256;
        f16 h, l; split(kv[j][0] * m0 + kv[j][1] * m1 + kv[j][2] * m2, h, l);
        kih[(long)tk * 512 + c] = h;
        kil[(long)tk * 512 + c] = l;
    }
}

// gate2: out[(tk,f,c)] = resi_p * (g2/(norm+EPS)), fp32 store. One block/token.
__global__ __launch_bounds__(256) void k_gate2(
    const f16* __restrict__ rph, const f16* __restrict__ rpl,
    const float* __restrict__ g2, float* __restrict__ out)
{
    const int t = threadIdx.x;
    const int tk = blockIdx.x;
    #pragma unroll
    for (int j = 0; j < 2; ++j) {
        const int c = t + j * 256;
        const long base = (long)tk * 1536 + c;
        const float r0 = (float)rph[base]        + (float)rpl[base];
        const float r1 = (float)rph[base + 512]  + (float)rpl[base + 512];
        const float r2 = (float)rph[base + 1024] + (float)rpl[base + 1024];
        const float nr = sqrtf(r0 * r0 + r1 * r1 + r2 * r2);
        const float gv = g2[(long)tk * 512 + c];
        const float s = (nr <= EPS) ? 1.f : gv / (nr + EPS);
        out[base]        = r0 * s;
        out[base + 512]  = r1 * s;
        out[base + 1024] = r2 * s;
    }
}

// ---------------------------------------------------------------------------
// q = LN(lq @ wq) per head (fp32 VALU, tiny), output f16 pair [h][qi][64].
__global__ __launch_bounds__(256) void k_qproj(
    const float* __restrict__ lq, const float* __restrict__ wq,
    const float* __restrict__ lns, const float* __restrict__ lnb,
    f16* __restrict__ qh, f16* __restrict__ ql)
{
    __shared__ float cs[QK];
    const int t = threadIdx.x;
    const int qi = blockIdx.x;
    const float* cp = lq + (long)qi * QK;
    for (int i = t; i < QK; i += 256) cs[i] = cp[i];
    __syncthreads();

    float a0 = 0, a1 = 0;
    #pragma unroll 4
    for (int d = 0; d < QK; ++d) {
        const float c = cs[d];
        a0 += c * wq[d * QK + t];
        a1 += c * wq[d * QK + t + 256];
    }
    float s0 = a0, q0 = a0 * a0, s1 = a1, q1 = a1 * a1;
    for (int off = 32; off; off >>= 1) {
        s0 += __shfl_down(s0, off); q0 += __shfl_down(q0, off);
        s1 += __shfl_down(s1, off); q1 += __shfl_down(q1, off);
    }
    s0 = __shfl(s0, 0); q0 = __shfl(q0, 0);
    s1 = __shfl(s1, 0); q1 = __shfl(q1, 0);
    const float mean0 = s0 * (1.f / 64.f), var0 = q0 * (1.f / 64.f) - mean0 * mean0;
    const float mean1 = s1 * (1.f / 64.f), var1 = q1 * (1.f / 64.f) - mean1 * mean1;
    const int e = t & 63;
    const float sc = lns[e], bi = lnb[e];
    const float r0 = (a0 - mean0) * rsqrtf(var0 + LNE) * sc + bi;
    const float r1 = (a1 - mean1) * rsqrtf(var1 + LNE) * sc + bi;
    const int h0 = t >> 6, h1 = h0 + 4;
    f16 h, l;
    split(r0, h, l);
    qh[((long)h0 * Qq + qi) * DH + e] = h;
    ql[((long)h0 * Qq + qi) * DH + e] = l;
    split(r1, h, l);
    qh[((long)h1 * Qq + qi) * DH + e] = h;
    ql[((long)h1 * Qq + qi) * DH + e] = l;
}

// ---------------------------------------------------------------------------
extern "C" void kernel_launch(void* const* d_in, const int* in_sizes, int n_in,
                              void* d_out, int out_size, void* d_ws, size_t ws_size,
                              hipStream_t stream)
{
    const float* x    = (const float*)d_in[0];
    const float* lq   = (const float*)d_in[1];
    const float* w_kv = (const float*)d_in[2];
    const float* w1a  = (const float*)d_in[3];
    const float* b1a  = (const float*)d_in[4];
    const float* w1b  = (const float*)d_in[5];
    const float* b1b  = (const float*)d_in[6];
    const float* wq   = (const float*)d_in[7];
    const float* wk   = (const float*)d_in[8];
    const float* wv   = (const float*)d_in[9];
    const float* lqs  = (const float*)d_in[10];
    const float* lqb  = (const float*)d_in[11];
    const float* lks  = (const float*)d_in[12];
    const float* lkb  = (const float*)d_in[13];
    const float* wo   = (const float*)d_in[14];
    const float* w2a  = (const float*)d_in[15];
    const float* b2a  = (const float*)d_in[16];
    const float* w2b  = (const float*)d_in[17];
    const float* b2b  = (const float*)d_in[18];

    char* ws = (char*)d_ws;
    // Layout (191.5 MB, lifetime-aliased):
    //  W  [0, 3670016): stage-1 weight pairs
    //  S  [3670016, 3817472): qhp | qlp | lsum
    //  W2 [3817472, 5914624): wo/w2a/w2b pairs (stage-2 weights)
    //  LP [5914624, 6045696): lsum partials (8 x 4096 f32)
    //  A1 [6946816, 40501248): normb pair -> kinv pair -> attn pair -> stage-2 bufs
    //  A2 [40501248, 57278464): hb pair -> resiT f32
    //  B  [57278464, 157941760): kv pair (pre -> gated in-place)
    //  D  [157941760, 191496192): g f32 -> k pair -> U pair
    f16* wkvTh = (f16*)(ws + 0);
    f16* wkvTl = (f16*)(ws + 262144);
    f16* w1aTh = (f16*)(ws + 524288);
    f16* w1aTl = (f16*)(ws + 786432);
    f16* w1bTh = (f16*)(ws + 1048576);
    f16* w1bTl = (f16*)(ws + 1310720);
    f16* wkTh  = (f16*)(ws + 1572864);
    f16* wkTl  = (f16*)(ws + 2097152);
    f16* wvTh  = (f16*)(ws + 2621440);
    f16* wvTl  = (f16*)(ws + 3145728);
    f16*   qhp   = (f16*)(ws + 3670016);
    f16*   qlp   = (f16*)(ws + 3735552);
    float* lsum  = (float*)(ws + 3801088);
    f16* woTh  = (f16*)(ws + 3817472);
    f16* woTl  = (f16*)(ws + 4341760);
    f16* w2aTh = (f16*)(ws + 4866048);
    f16* w2aTl = (f16*)(ws + 5128192);
    f16* w2bTh = (f16*)(ws + 5390336);
    f16* w2bTl = (f16*)(ws + 5652480);
    float* lsum_part = (float*)(ws + 5914624);  // 131072 B
    f16* nh    = (f16*)(ws + 6946816);
    f16* nl    = (f16*)(ws + 23724032);
    f16* kih   = nh;
    f16* kil   = nl;
    f16* ath   = (f16*)(ws + 6946816);
    f16* atl   = (f16*)(ws + 23724032);
    // stage-2 buffers (A1 region; attn dead after step 10)
    f16*   rph  = (f16*)(ws + 6946816);    // 1,572,864
    f16*   rpl  = (f16*)(ws + 8519680);    // 1,572,864
    f16*   n2h  = (f16*)(ws + 10092544);   //   524,288
    f16*   n2l  = (f16*)(ws + 10616832);   //   524,288
    f16*   h2h  = (f16*)(ws + 11141120);   //   262,144
    f16*   h2l  = (f16*)(ws + 11403264);   //   262,144
    float* g2   = (float*)(ws + 11665408); // 1,048,576
    f16* hbh   = (f16*)(ws + 40501248);
    f16* hbl   = (f16*)(ws + 48889856);
    float* resiT = (float*)(ws + 40501248); // aliases hb (dead after step 5)
    f16* kvh   = (f16*)(ws + 57278464);
    f16* kvl   = (f16*)(ws + 107610112);
    float* g    = (float*)(ws + 157941760);
    f16* khb   = (f16*)(ws + 157941760);
    f16* klb   = (f16*)(ws + 174718976);
    f16* Uh    = (f16*)(ws + 157941760);
    f16* Ul    = (f16*)(ws + 170524672);
    float* out  = (float*)d_out;

    // 1. weight casts (transposed pairs)
    k_castTpair<<<512,  256, 0, stream>>>(w_kv, wkvTh, wkvTl, Dd, QK);
    k_castTpair<<<512,  256, 0, stream>>>(w1a,  w1aTh, w1aTl, QK, 256);
    k_castTpair<<<512,  256, 0, stream>>>(w1b,  w1bTh, w1bTl, 256, QK);
    k_castTpair<<<1024, 256, 0, stream>>>(wk,   wkTh,  wkTl,  QK, QK);
    k_castTpair<<<1024, 256, 0, stream>>>(wv,   wvTh,  wvTl,  QK, QK);
    k_castTpair<<<1024, 256, 0, stream>>>(wo,   woTh,  woTl,  Vd, Vd);
    k_castTpair<<<512,  256, 0, stream>>>(w2a,  w2aTh, w2aTl, Vd, 256);
    k_castTpair<<<512,  256, 0, stream>>>(w2b,  w2bTh, w2bTl, 256, Vd);

    // 2. kv_pre = x @ w_kv -> kv pair (barrier-free reg-streaming GEMM)
    k_kvstream<<<768, 128, 0, stream>>>(x, wkvTh, wkvTl, kvh, kvl);
    // 3. norm
    k_norm<<<32768, 256, 0, stream>>>(kvh, kvl, nh, nl);
    // 4. h = leaky(norm @ w1a + b1a) -> hb pair
    k_gemm3<0, 1><<<dim3(128, 4), 256, 0, stream>>>(
        nullptr, nh, nl, w1aTh, w1aTl, 256, QK, hbh, hbl, b1a, nullptr);
    // 5. g = h @ w1b + b1b -> f32
    k_gemm3<0, 2><<<dim3(128, 8), 256, 0, stream>>>(
        nullptr, hbh, hbl, w1bTh, w1bTl, QK, 256, g, nullptr, b1b, nullptr);
    // 6. gate in-place + kinv pair
    k_gate<<<NT, 256, 0, stream>>>(kvh, kvl, g, kih, kil);
    // 7. k = LN(kinv @ wk) -> k pair [h][tok][64]
    k_gemm3<0, 3><<<dim3(128, 8), 256, 0, stream>>>(
        nullptr, kih, kil, wkTh, wkTl, QK, QK, khb, klb, lks, lkb);
    // 8. q -> pair
    k_qproj<<<Qq, 256, 0, stream>>>(lq, wq, lqs, lqb, qhp, qlp);
    // 9. attn: MFMA QK^T + exp + partial rowsum (512 blocks = 64 hb x 8 parts)
    k_attn_mfma<<<512, 256, 0, stream>>>(qhp, qlp, khb, klb, ath, atl, lsum_part);
    // 9b. reduce partial rowsums
    k_lsum_reduce<<<16, 256, 0, stream>>>(lsum_part, lsum);
    // 10. U = (attn @ kv) / lsum -> U pair (dist-2 reg pipeline, swizzled LDS)
    k_gemm3T<<<512, 512, 0, stream>>>(ath, atl, kvh, kvl, lsum, Uh, Ul);
    // 11. resi = U @ wv -> resiT f32 [(b,q,f)][512]
    k_gemm3<0, 5><<<dim3(12, 8), 256, 0, stream>>>(
        nullptr, Uh, Ul, wvTh, wvTl, 64, QK, resiT, nullptr, nullptr, nullptr);
    // 12a. resi_p = resiT @ w_out -> pair  [1536,512]
    k_gemm3<1, 0><<<dim3(12, 8), 256, 0, stream>>>(
        resiT, nullptr, nullptr, woTh, woTl, Vd, Vd, rph, rpl, nullptr, nullptr);
    // 12b. norm2 over f (512 tokens)
    k_norm<<<1024, 256, 0, stream>>>(rph, rpl, n2h, n2l);
    // 12c. h2 = leaky(norm2 @ w2a + b2a) -> pair [512,256]
    k_gemm3<0, 1><<<dim3(4, 4), 256, 0, stream>>>(
        nullptr, n2h, n2l, w2aTh, w2aTl, 256, Vd, h2h, h2l, b2a, nullptr);
    // 12d. g2 = h2 @ w2b + b2b -> f32 [512,512]
    k_gemm3<0, 2><<<dim3(4, 8), 256, 0, stream>>>(
        nullptr, h2h, h2l, w2bTh, w2bTl, Vd, 256, g2, nullptr, b2b, nullptr);
    // 12e. out = resi_p * g2/(norm+EPS), fp32
    k_gate2<<<B * Qq, 256, 0, stream>>>(rph, rpl, g2, out);
}

// Round 9
// 561.713 us; speedup vs baseline: 1.1313x; 1.1313x over previous
//
#include <hip/hip_runtime.h>
#include <hip/hip_bf16.h>

typedef _Float16 f16;
typedef __attribute__((ext_vector_type(8))) _Float16 f16x8;
typedef __attribute__((ext_vector_type(4))) _Float16 f16x4;
typedef __attribute__((ext_vector_type(2))) _Float16 f16x2;
typedef __attribute__((ext_vector_type(4))) float floatx4;

// Problem constants
constexpr int B  = 8;
constexpr int N  = 2048;
constexpr int Fv = 3;
constexpr int Dd = 256;
constexpr int QK = 512;
constexpr int Vd = 512;
constexpr int Hh = 8;
constexpr int Qq = 64;
constexpr int DH = 64;
constexpr int NT = B * N;          // 16384 tokens
constexpr float EPS = 1e-6f;
constexpr float NEG = 0.2f;
constexpr float LNE = 1e-6f;

#define DEV static __device__ __forceinline__
DEV void split(float v, f16& h, f16& l) { h = (f16)v; l = (f16)(v - (float)h); }

// ---------------------------------------------------------------------------
// Split-fp16 3-mul GEMM (effective fp32 accuracy): C = A[M,K] @ B[K,N]
// A as (Ah,Al) f16 pairs (ASRC=0) or fp32 split on the fly (ASRC=1).
// Bt = B^T row-major [N,K] as (Bh,Bl) pairs.
// Block 256 thr = 4 waves; tile 128M x 64N; wave = 32 rows x 64 cols.
// EPI: 0 pair store                 1 +bias,leaky -> pair
//      2 +bias -> f32               3 per-64col LN -> f16 pair [h][tok][64]
//      5 PV2: store f32 resiT[(b,q,f)][512] at col h*64+
// ---------------------------------------------------------------------------
template<int ASRC, int EPI>
__global__ __launch_bounds__(256) void k_gemm3(
    const float* __restrict__ A32,
    const f16* __restrict__ Ah, const f16* __restrict__ Al,
    const f16* __restrict__ Bh, const f16* __restrict__ Bl,
    int Ndim, int Kdim, void* __restrict__ C1, void* __restrict__ C2,
    const float* __restrict__ e0, const float* __restrict__ e1)
{
    __shared__ __align__(16) f16 Ash[128][72];
    __shared__ __align__(16) f16 Asl[128][72];
    __shared__ __align__(16) f16 Bsh[64][72];
    __shared__ __align__(16) f16 Bsl[64][72];

    const int t = threadIdx.x;
    long row0; int col0, boff;
    if (EPI == 5) { row0 = (long)blockIdx.y * 1536 + (long)blockIdx.x * 128; col0 = 0; boff = blockIdx.y * 64; }
    else          { row0 = (long)blockIdx.x * 128; col0 = blockIdx.y * 64; boff = 0; }

    floatx4 acc0[4], acc1[4];
    #pragma unroll
    for (int nt = 0; nt < 4; ++nt)
        #pragma unroll
        for (int j = 0; j < 4; ++j) { acc0[nt][j] = 0.f; acc1[nt][j] = 0.f; }

    const int L = t & 63, w = t >> 6;
    const int kq = (L >> 4) << 3;

    for (int k0 = 0; k0 < Kdim; k0 += 64) {
        if constexpr (ASRC == 1) {
            #pragma unroll
            for (int j = 0; j < 8; ++j) {
                const int i = t + j * 256;
                const int r = i >> 4, c4 = (i & 15) << 2;
                const floatx4 v = *(const floatx4*)&A32[(row0 + r) * Kdim + k0 + c4];
                f16x4 h4, l4;
                #pragma unroll
                for (int m = 0; m < 4; ++m) { h4[m] = (f16)v[m]; l4[m] = (f16)(v[m] - (float)h4[m]); }
                *(f16x4*)&Ash[r][c4] = h4;
                *(f16x4*)&Asl[r][c4] = l4;
            }
        } else {
            #pragma unroll
            for (int j = 0; j < 4; ++j) {
                const int i = t + j * 256;
                const int r = i >> 3, c8 = (i & 7) << 3;
                *(f16x8*)&Ash[r][c8] = *(const f16x8*)&Ah[(row0 + r) * (long)Kdim + k0 + c8];
                *(f16x8*)&Asl[r][c8] = *(const f16x8*)&Al[(row0 + r) * (long)Kdim + k0 + c8];
            }
        }
        #pragma unroll
        for (int j = 0; j < 2; ++j) {
            const int i = t + j * 256;
            const int r = i >> 3, c8 = (i & 7) << 3;
            *(f16x8*)&Bsh[r][c8] = *(const f16x8*)&Bh[(long)(boff + col0 + r) * Kdim + k0 + c8];
            *(f16x8*)&Bsl[r][c8] = *(const f16x8*)&Bl[(long)(boff + col0 + r) * Kdim + k0 + c8];
        }
        __syncthreads();
        #pragma unroll
        for (int kk = 0; kk < 64; kk += 32) {
            const f16x8 ah0 = *(const f16x8*)&Ash[w * 32 + (L & 15)][kk + kq];
            const f16x8 al0 = *(const f16x8*)&Asl[w * 32 + (L & 15)][kk + kq];
            const f16x8 ah1 = *(const f16x8*)&Ash[w * 32 + 16 + (L & 15)][kk + kq];
            const f16x8 al1 = *(const f16x8*)&Asl[w * 32 + 16 + (L & 15)][kk + kq];
            #pragma unroll
            for (int nt = 0; nt < 4; ++nt) {
                const f16x8 bh = *(const f16x8*)&Bsh[nt * 16 + (L & 15)][kk + kq];
                const f16x8 bl = *(const f16x8*)&Bsl[nt * 16 + (L & 15)][kk + kq];
                acc0[nt] = __builtin_amdgcn_mfma_f32_16x16x32_f16(ah0, bh, acc0[nt], 0, 0, 0);
                acc0[nt] = __builtin_amdgcn_mfma_f32_16x16x32_f16(ah0, bl, acc0[nt], 0, 0, 0);
                acc0[nt] = __builtin_amdgcn_mfma_f32_16x16x32_f16(al0, bh, acc0[nt], 0, 0, 0);
                acc1[nt] = __builtin_amdgcn_mfma_f32_16x16x32_f16(ah1, bh, acc1[nt], 0, 0, 0);
                acc1[nt] = __builtin_amdgcn_mfma_f32_16x16x32_f16(ah1, bl, acc1[nt], 0, 0, 0);
                acc1[nt] = __builtin_amdgcn_mfma_f32_16x16x32_f16(al1, bh, acc1[nt], 0, 0, 0);
            }
        }
        __syncthreads();
    }

    // C/D layout: col = lane&15, row = (lane>>4)*4 + reg
    const int cb = L & 15;
    #pragma unroll
    for (int rt = 0; rt < 2; ++rt) {
        const floatx4* acc = rt ? acc1 : acc0;
        const int rb = w * 32 + rt * 16 + ((L >> 4) << 2);
        if constexpr (EPI == 0) {
            f16* Ch = (f16*)C1; f16* Cl = (f16*)C2;
            #pragma unroll
            for (int nt = 0; nt < 4; ++nt)
                #pragma unroll
                for (int r = 0; r < 4; ++r) {
                    f16 h, l; split(acc[nt][r], h, l);
                    const long o = (row0 + rb + r) * (long)Ndim + col0 + nt * 16 + cb;
                    Ch[o] = h; Cl[o] = l;
                }
        } else if constexpr (EPI == 1) {
            f16* Ch = (f16*)C1; f16* Cl = (f16*)C2;
            #pragma unroll
            for (int nt = 0; nt < 4; ++nt) {
                const int col = col0 + nt * 16 + cb;
                const float bias = e0[col];
                #pragma unroll
                for (int r = 0; r < 4; ++r) {
                    float v = acc[nt][r] + bias;
                    v = v > 0.f ? v : NEG * v;
                    f16 h, l; split(v, h, l);
                    const long o = (row0 + rb + r) * (long)Ndim + col;
                    Ch[o] = h; Cl[o] = l;
                }
            }
        } else if constexpr (EPI == 2) {
            float* C = (float*)C1;
            #pragma unroll
            for (int nt = 0; nt < 4; ++nt) {
                const int col = col0 + nt * 16 + cb;
                const float bias = e0[col];
                #pragma unroll
                for (int r = 0; r < 4; ++r)
                    C[(row0 + rb + r) * (long)Ndim + col] = acc[nt][r] + bias;
            }
        } else if constexpr (EPI == 3) {
            f16* Ch = (f16*)C1; f16* Cl = (f16*)C2;
            const int h = blockIdx.y;
            #pragma unroll
            for (int r = 0; r < 4; ++r) {
                float s = 0.f, q = 0.f;
                #pragma unroll
                for (int nt = 0; nt < 4; ++nt) { const float v = acc[nt][r]; s += v; q += v * v; }
                s += __shfl_xor(s, 1); q += __shfl_xor(q, 1);
                s += __shfl_xor(s, 2); q += __shfl_xor(q, 2);
                s += __shfl_xor(s, 4); q += __shfl_xor(q, 4);
                s += __shfl_xor(s, 8); q += __shfl_xor(q, 8);
                const float mean = s * (1.f / 64.f);
                const float var  = q * (1.f / 64.f) - mean * mean;
                const float rs   = rsqrtf(var + LNE);
                #pragma unroll
                for (int nt = 0; nt < 4; ++nt) {
                    const int col = nt * 16 + cb;
                    const float v = (acc[nt][r] - mean) * rs * e0[col] + e1[col];
                    f16 hh, ll; split(v, hh, ll);
                    const long o = ((long)h * NT + row0 + rb + r) * 64 + col;
                    Ch[o] = hh; Cl[o] = ll;
                }
            }
        } else {  // EPI == 5
            float* C = (float*)C1;
            #pragma unroll
            for (int nt = 0; nt < 4; ++nt)
                #pragma unroll
                for (int r = 0; r < 4; ++r) {
                    const long rr = row0 + rb + r - (long)blockIdx.y * 1536;
                    C[rr * 512 + boff + nt * 16 + cb] = acc[nt][r];
                }
        }
    }
}

// ---------------------------------------------------------------------------
// Round-8: step-2 GEMM (kv_pre = x @ w_kv) as a port of the PROVEN
// k_gemm3T structure (rounds 3+5+6): 512 thr / 8 waves, tile 128x128,
// BK=32 -> 8 pipeline iters (vs 4 for the old BK=64 path), LDS dbuf with
// ONE barrier/tile, dist-2 RA/RB register sets (WRITE waits only on loads
// a full iteration old -> dependency-driven counted vmcnt), XOR granule
// swizzle (2-way staging writes = free; fragment reads conflict-free,
// same per-lane-constant kqs algebra). fp32->f16 split happens in-register
// inside WRITE (overlaps compute). B^T pair is already [col][k] -> no
// transpose in staging, coalesced 16B strips. LDS = 64 KB exactly ->
// 2 blocks/CU = 16 waves/CU. Grid 384 rowblk x 4 colblk; consecutive
// blocks share the x row-slice (L2/L3 locality). Accumulation order
// identical to the old ASRC=1 path -> same numerics.
// (Round-7's reg-streaming k_kvstream failed: 6 waves/CU + scattered
// 16B gathers = latency starvation; MfmaUtil 10.5, everything idle.)
// ---------------------------------------------------------------------------
__global__ __launch_bounds__(512, 4) void k_kv2(
    const float* __restrict__ x,
    const f16* __restrict__ Bh, const f16* __restrict__ Bl,
    f16* __restrict__ Ch, f16* __restrict__ Cl)
{
    __shared__ __align__(16) f16 Ash[2][128][32];
    __shared__ __align__(16) f16 Asl[2][128][32];
    __shared__ __align__(16) f16 Bsh[2][128][32];
    __shared__ __align__(16) f16 Bsl[2][128][32];

    const int t = threadIdx.x;
    const int bx = blockIdx.x;
    const long row0 = (long)(bx >> 2) * 128;
    const int col0 = (bx & 3) * 128;

    // staging: thread -> (row/col sr 0..127, granule sg 0..3), swizzled
    const int sr = t >> 2;
    const int sg = t & 3;
    const int spg = ((sg ^ ((sr >> 1) & 3)) << 3);   // phys halfword offset
    const float* ap  = x  + (row0 + sr) * 256 + sg * 8;
    const f16*   bph = Bh + (long)(col0 + sr) * 256 + sg * 8;
    const f16*   bpl = Bl + (long)(col0 + sr) * 256 + sg * 8;

    floatx4 acc[2][4];
    #pragma unroll
    for (int rg = 0; rg < 2; ++rg)
        #pragma unroll
        for (int nt = 0; nt < 4; ++nt)
            #pragma unroll
            for (int j = 0; j < 4; ++j) acc[rg][nt][j] = 0.f;

    const int L = t & 63, w = t >> 6;
    const int wr = (w >> 1) << 5;    // 0,32,64,96
    const int wc = (w & 1) << 6;     // 0,64
    // swizzled fragment-read column (per-lane constant, all reads)
    const int kqs = (((L >> 4) ^ ((L >> 1) & 3)) << 3);

    // dist-2 staging register sets
    floatx4 pa0, pa1; f16x8 pbh, pbl;   // RA
    floatx4 qa0, qa1; f16x8 qbh, qbl;   // RB

    auto LOADA = [&](int k0) {
        pa0 = *(const floatx4*)&ap[k0];
        pa1 = *(const floatx4*)&ap[k0 + 4];
        pbh = *(const f16x8*)&bph[k0];
        pbl = *(const f16x8*)&bpl[k0];
    };
    auto LOADB = [&](int k0) {
        qa0 = *(const floatx4*)&ap[k0];
        qa1 = *(const floatx4*)&ap[k0 + 4];
        qbh = *(const f16x8*)&bph[k0];
        qbl = *(const f16x8*)&bpl[k0];
    };
    auto WRITEA = [&](int buf) {
        f16x8 h8, l8;
        #pragma unroll
        for (int m = 0; m < 4; ++m) {
            f16 hh, ll;
            split(pa0[m], hh, ll); h8[m] = hh;     l8[m] = ll;
            split(pa1[m], hh, ll); h8[m + 4] = hh; l8[m + 4] = ll;
        }
        *(f16x8*)&Ash[buf][sr][spg] = h8;
        *(f16x8*)&Asl[buf][sr][spg] = l8;
        *(f16x8*)&Bsh[buf][sr][spg] = pbh;
        *(f16x8*)&Bsl[buf][sr][spg] = pbl;
    };
    auto WRITEB = [&](int buf) {
        f16x8 h8, l8;
        #pragma unroll
        for (int m = 0; m < 4; ++m) {
            f16 hh, ll;
            split(qa0[m], hh, ll); h8[m] = hh;     l8[m] = ll;
            split(qa1[m], hh, ll); h8[m + 4] = hh; l8[m + 4] = ll;
        }
        *(f16x8*)&Ash[buf][sr][spg] = h8;
        *(f16x8*)&Asl[buf][sr][spg] = l8;
        *(f16x8*)&Bsh[buf][sr][spg] = qbh;
        *(f16x8*)&Bsl[buf][sr][spg] = qbl;
    };
    auto COMPUTE = [&](int buf) {
        const f16x8 ah0 = *(const f16x8*)&Ash[buf][wr + (L & 15)][kqs];
        const f16x8 al0 = *(const f16x8*)&Asl[buf][wr + (L & 15)][kqs];
        const f16x8 ah1 = *(const f16x8*)&Ash[buf][wr + 16 + (L & 15)][kqs];
        const f16x8 al1 = *(const f16x8*)&Asl[buf][wr + 16 + (L & 15)][kqs];
        #pragma unroll
        for (int nt = 0; nt < 4; ++nt) {
            const f16x8 bh = *(const f16x8*)&Bsh[buf][wc + nt * 16 + (L & 15)][kqs];
            const f16x8 bl = *(const f16x8*)&Bsl[buf][wc + nt * 16 + (L & 15)][kqs];
            acc[0][nt] = __builtin_amdgcn_mfma_f32_16x16x32_f16(ah0, bh, acc[0][nt], 0, 0, 0);
            acc[0][nt] = __builtin_amdgcn_mfma_f32_16x16x32_f16(ah0, bl, acc[0][nt], 0, 0, 0);
            acc[0][nt] = __builtin_amdgcn_mfma_f32_16x16x32_f16(al0, bh, acc[0][nt], 0, 0, 0);
            acc[1][nt] = __builtin_amdgcn_mfma_f32_16x16x32_f16(ah1, bh, acc[1][nt], 0, 0, 0);
            acc[1][nt] = __builtin_amdgcn_mfma_f32_16x16x32_f16(ah1, bl, acc[1][nt], 0, 0, 0);
            acc[1][nt] = __builtin_amdgcn_mfma_f32_16x16x32_f16(al1, bh, acc[1][nt], 0, 0, 0);
        }
    };

    // prologue: tile0 -> buf0 (via RA); preload tile1 into RA
    LOADA(0);
    WRITEA(0);
    LOADA(32);
    __syncthreads();
    // invariant (even tt): buf0 = tile tt, RA = tile tt+1

    for (int tt = 0; tt < 8; tt += 2) {
        if (tt + 2 < 8) LOADB((tt + 2) * 32);    // tile tt+2 -> RB (in flight)
        COMPUTE(0);                               // tile tt
        if (tt + 1 < 8) WRITEA(1);                // tile tt+1 (RA, 1 iter old)
        __syncthreads();
        if (tt + 3 < 8) LOADA((tt + 3) * 32);    // tile tt+3 -> RA
        COMPUTE(1);                               // tile tt+1
        if (tt + 2 < 8) WRITEB(0);                // tile tt+2 (RB)
        __syncthreads();
    }

    // epilogue: pair store; C/D layout col=lane&15, row=(lane>>4)*4+reg
    const int cb = L & 15;
    #pragma unroll
    for (int rg = 0; rg < 2; ++rg) {
        const int rb = wr + rg * 16 + ((L >> 4) << 2);
        #pragma unroll
        for (int nt = 0; nt < 4; ++nt)
            #pragma unroll
            for (int r = 0; r < 4; ++r) {
                f16 h, l; split(acc[rg][nt][r], h, l);
                const long o = (row0 + rb + r) * 512 + col0 + wc + nt * 16 + cb;
                Ch[o] = h; Cl[o] = l;
            }
    }
}

// ---------------------------------------------------------------------------
// Attention scores via MFMA. Grid 512 = 64 hb x 8 n-parts (2/CU).
// Each block does 4 K-tiles of a 256-token slice; partial row-sums go to
// lsum_part[part][hb*64+q], reduced by k_lsum_reduce.
// S[q,n] = (qv . k)/8 ; p = exp(S) (no max-sub: |S|<=8 after LN).
// ---------------------------------------------------------------------------
__global__ __launch_bounds__(256) void k_attn_mfma(
    const f16* __restrict__ qh, const f16* __restrict__ ql,
    const f16* __restrict__ kh, const f16* __restrict__ kl,
    f16* __restrict__ ath, f16* __restrict__ atl, float* __restrict__ lsum_part)
{
    __shared__ __align__(16) f16 Qh[64][72], Ql[64][72];
    __shared__ __align__(16) f16 Kh[64][72], Kl[64][72];

    const int t = threadIdx.x;
    const int bx = blockIdx.x;
    const int hb = bx & 63;
    const int part = bx >> 6;        // 0..7
    const int h = hb >> 3;
    const int L = t & 63, w = t >> 6;
    const int kq = (L >> 4) << 3;

    #pragma unroll
    for (int j = 0; j < 2; ++j) {
        const int i = t + j * 256;
        const int r = i >> 3, c8 = (i & 7) << 3;
        *(f16x8*)&Qh[r][c8] = *(const f16x8*)&qh[((long)h * 64 + r) * 64 + c8];
        *(f16x8*)&Ql[r][c8] = *(const f16x8*)&ql[((long)h * 64 + r) * 64 + c8];
    }
    __syncthreads();

    f16x8 qah[2], qal[2];
    #pragma unroll
    for (int kc = 0; kc < 2; ++kc) {
        qah[kc] = *(const f16x8*)&Qh[w * 16 + (L & 15)][kc * 32 + kq];
        qal[kc] = *(const f16x8*)&Ql[w * 16 + (L & 15)][kc * 32 + kq];
    }

    float psum[4] = {0.f, 0.f, 0.f, 0.f};
    const int rowb = w * 16 + ((L >> 4) << 2);

    for (int nt0 = 0; nt0 < 4; ++nt0) {
        const int n0 = part * 256 + nt0 * 64;
        __syncthreads();
        #pragma unroll
        for (int j = 0; j < 2; ++j) {
            const int i = t + j * 256;
            const int r = i >> 3, c8 = (i & 7) << 3;
            *(f16x8*)&Kh[r][c8] = *(const f16x8*)&kh[((long)hb * N + n0 + r) * 64 + c8];
            *(f16x8*)&Kl[r][c8] = *(const f16x8*)&kl[((long)hb * N + n0 + r) * 64 + c8];
        }
        __syncthreads();

        floatx4 acc[4];
        #pragma unroll
        for (int nt = 0; nt < 4; ++nt)
            #pragma unroll
            for (int j = 0; j < 4; ++j) acc[nt][j] = 0.f;

        #pragma unroll
        for (int kc = 0; kc < 2; ++kc) {
            #pragma unroll
            for (int nt = 0; nt < 4; ++nt) {
                const f16x8 bh = *(const f16x8*)&Kh[nt * 16 + (L & 15)][kc * 32 + kq];
                const f16x8 bl = *(const f16x8*)&Kl[nt * 16 + (L & 15)][kc * 32 + kq];
                acc[nt] = __builtin_amdgcn_mfma_f32_16x16x32_f16(qah[kc], bh, acc[nt], 0, 0, 0);
                acc[nt] = __builtin_amdgcn_mfma_f32_16x16x32_f16(qah[kc], bl, acc[nt], 0, 0, 0);
                acc[nt] = __builtin_amdgcn_mfma_f32_16x16x32_f16(qal[kc], bh, acc[nt], 0, 0, 0);
            }
        }

        #pragma unroll
        for (int nt = 0; nt < 4; ++nt)
            #pragma unroll
            for (int r = 0; r < 4; ++r) {
                const float p = __expf(acc[nt][r] * 0.125f);
                psum[r] += p;
                f16 hh, ll; split(p, hh, ll);
                const long o = ((long)hb * 64 + rowb + r) * N + n0 + nt * 16 + (L & 15);
                ath[o] = hh; atl[o] = ll;
            }
    }

    #pragma unroll
    for (int r = 0; r < 4; ++r) {
        float s = psum[r];
        s += __shfl_xor(s, 1);
        s += __shfl_xor(s, 2);
        s += __shfl_xor(s, 4);
        s += __shfl_xor(s, 8);
        if ((L & 15) == 0) lsum_part[part * 4096 + hb * 64 + rowb + r] = s;
    }
}

// lsum[i] = sum_p lsum_part[p][i] (deterministic, 16 blocks x 256)
__global__ void k_lsum_reduce(const float* __restrict__ part, float* __restrict__ lsum)
{
    const int i = blockIdx.x * 256 + threadIdx.x;
    float s = 0.f;
    #pragma unroll
    for (int p = 0; p < 8; ++p) s += part[p * 4096 + i];
    lsum[i] = s;
}

// ---------------------------------------------------------------------------
// PV1: U[hb*64+q, fd] = (1/lsum[row]) * sum_n p[row,n] * kv[b][n, fd]
// Dist-2 register pipeline (round-6 WIN): WRITE consumes regs loaded a full
// iteration earlier -> dependency-driven counted vmcnt. Swizzled LDS
// (round-5) keeps reads conflict-free. Dbuf BK=32, 1 barrier/tile;
// LDS 56 KB; 2 blocks/CU; wave 32x48.
// ---------------------------------------------------------------------------
__global__ __launch_bounds__(512, 4) void k_gemm3T(
    const f16* __restrict__ Ah, const f16* __restrict__ Al,
    const f16* __restrict__ Bh, const f16* __restrict__ Bl,
    const float* __restrict__ lsum,
    f16* __restrict__ Uh, f16* __restrict__ Ul)
{
    __shared__ __align__(16) f16 Ash[2][128][32];
    __shared__ __align__(16) f16 Asl[2][128][32];
    __shared__ __align__(16) f16 Bsh[2][96][32];
    __shared__ __align__(16) f16 Bsl[2][96][32];

    const int t = threadIdx.x;
    const int by = blockIdx.x;
    const int b = by & 7;
    const int rest = by >> 3;        // 0..63
    const int ct = rest & 15;        // 96-col chunk
    const int hp = rest >> 4;        // 0..3
    const int hb0 = b + 16 * hp;
    const int hb1 = hb0 + 8;

    // A staging: thread -> (row ar, granule t&3); swizzled granule constant
    const int ar = t >> 2;                                // 0..127
    const int apg = (((t & 3) ^ ((t >> 3) & 3)) << 3);    // phys halfword off
    const f16* Arh = (ar < 64)
        ? Ah + ((long)hb0 * 64 + ar) * 2048
        : Ah + ((long)hb1 * 64 + (ar - 64)) * 2048;
    const f16* Arl = (ar < 64)
        ? Al + ((long)hb0 * 64 + ar) * 2048
        : Al + ((long)hb1 * 64 + (ar - 64)) * 2048;
    const int aseg = (t & 3) << 3;       // logical k-offset in global

    // B staging (transpose): threads 0..191, each 2 k-rows x 8 cols
    const f16* Bbh = Bh + (long)b * 2048 * 1536 + ct * 96;
    const f16* Bbl = Bl + (long)b * 2048 * 1536 + ct * 96;
    const bool bstage = t < 192;
    const int k2 = t & 15;               // k-pair 0..15
    const int cg = t >> 4;               // col group 0..11 (valid for t<192)

    floatx4 acc[2][3];
    #pragma unroll
    for (int i = 0; i < 2; ++i)
        #pragma unroll
        for (int nt = 0; nt < 3; ++nt)
            #pragma unroll
            for (int j = 0; j < 4; ++j) acc[i][nt][j] = 0.f;

    const int L = t & 63, w = t >> 6;
    const int wr = (w >> 1) << 5;        // 0,32,64,96
    const int wc = (w & 1) * 48;         // 0,48
    // swizzled fragment-read column: logical granule L>>4, row-XOR (L>>1)&3
    const int kqs = (((L >> 4) ^ ((L >> 1) & 3)) << 3);

    // two named staging-register sets (static roles, unroll x2)
    f16x8 pAh, pAl, pB0h, pB1h, pB0l, pB1l;   // set RA
    f16x8 qAh, qAl, qB0h, qB1h, qB0l, qB1l;   // set RB

    auto LOADA = [&](int k0) {
        pAh = *(const f16x8*)&Arh[k0 + aseg];
        pAl = *(const f16x8*)&Arl[k0 + aseg];
        if (bstage) {
            const long r0 = (long)(k0 + 2 * k2) * 1536 + cg * 8;
            pB0h = *(const f16x8*)&Bbh[r0];
            pB1h = *(const f16x8*)&Bbh[r0 + 1536];
            pB0l = *(const f16x8*)&Bbl[r0];
            pB1l = *(const f16x8*)&Bbl[r0 + 1536];
        }
    };
    auto LOADB = [&](int k0) {
        qAh = *(const f16x8*)&Arh[k0 + aseg];
        qAl = *(const f16x8*)&Arl[k0 + aseg];
        if (bstage) {
            const long r0 = (long)(k0 + 2 * k2) * 1536 + cg * 8;
            qB0h = *(const f16x8*)&Bbh[r0];
            qB1h = *(const f16x8*)&Bbh[r0 + 1536];
            qB0l = *(const f16x8*)&Bbl[r0];
            qB1l = *(const f16x8*)&Bbl[r0 + 1536];
        }
    };
    auto WRITEA = [&](int buf) {
        *(f16x8*)&Ash[buf][ar][apg] = pAh;
        *(f16x8*)&Asl[buf][ar][apg] = pAl;
        if (bstage) {
            #pragma unroll
            for (int j = 0; j < 8; ++j) {
                const int hw = ((((k2 >> 2) ^ ((j >> 1) & 3)) << 3) | ((k2 & 3) << 1));
                f16x2 ph; ph[0] = pB0h[j]; ph[1] = pB1h[j];
                f16x2 pl; pl[0] = pB0l[j]; pl[1] = pB1l[j];
                *(f16x2*)&Bsh[buf][cg * 8 + j][hw] = ph;
                *(f16x2*)&Bsl[buf][cg * 8 + j][hw] = pl;
            }
        }
    };
    auto WRITEB = [&](int buf) {
        *(f16x8*)&Ash[buf][ar][apg] = qAh;
        *(f16x8*)&Asl[buf][ar][apg] = qAl;
        if (bstage) {
            #pragma unroll
            for (int j = 0; j < 8; ++j) {
                const int hw = ((((k2 >> 2) ^ ((j >> 1) & 3)) << 3) | ((k2 & 3) << 1));
                f16x2 ph; ph[0] = qB0h[j]; ph[1] = qB1h[j];
                f16x2 pl; pl[0] = qB0l[j]; pl[1] = qB1l[j];
                *(f16x2*)&Bsh[buf][cg * 8 + j][hw] = ph;
                *(f16x2*)&Bsl[buf][cg * 8 + j][hw] = pl;
            }
        }
    };
    auto COMPUTE = [&](int buf) {
        const f16x8 ah0 = *(const f16x8*)&Ash[buf][wr + (L & 15)][kqs];
        const f16x8 al0 = *(const f16x8*)&Asl[buf][wr + (L & 15)][kqs];
        const f16x8 ah1 = *(const f16x8*)&Ash[buf][wr + 16 + (L & 15)][kqs];
        const f16x8 al1 = *(const f16x8*)&Asl[buf][wr + 16 + (L & 15)][kqs];
        #pragma unroll
        for (int nt = 0; nt < 3; ++nt) {
            const f16x8 bh = *(const f16x8*)&Bsh[buf][wc + nt * 16 + (L & 15)][kqs];
            const f16x8 bl = *(const f16x8*)&Bsl[buf][wc + nt * 16 + (L & 15)][kqs];
            acc[0][nt] = __builtin_amdgcn_mfma_f32_16x16x32_f16(ah0, bh, acc[0][nt], 0, 0, 0);
            acc[0][nt] = __builtin_amdgcn_mfma_f32_16x16x32_f16(ah0, bl, acc[0][nt], 0, 0, 0);
            acc[0][nt] = __builtin_amdgcn_mfma_f32_16x16x32_f16(al0, bh, acc[0][nt], 0, 0, 0);
            acc[1][nt] = __builtin_amdgcn_mfma_f32_16x16x32_f16(ah1, bh, acc[1][nt], 0, 0, 0);
            acc[1][nt] = __builtin_amdgcn_mfma_f32_16x16x32_f16(ah1, bl, acc[1][nt], 0, 0, 0);
            acc[1][nt] = __builtin_amdgcn_mfma_f32_16x16x32_f16(al1, bh, acc[1][nt], 0, 0, 0);
        }
    };

    // prologue: tile0 -> buf0 (via RA), then preload tile1 into RA
    LOADA(0);
    WRITEA(0);
    LOADA(32);
    __syncthreads();
    // invariant at loop top (even tt): buf[tt&1] holds tile tt, RA holds tile tt+1

    for (int tt = 0; tt < 64; tt += 2) {
        // even half: compute tile tt (buf0), write tile tt+1 (RA) -> buf1
        if (tt + 2 < 64) LOADB((tt + 2) * 32);   // tile tt+2 -> RB (stays in flight)
        COMPUTE(0);
        if (tt + 1 < 64) WRITEA(1);              // waits only RA's loads (1 iter old)
        __syncthreads();
        // odd half: compute tile tt+1 (buf1), write tile tt+2 (RB) -> buf0
        if (tt + 3 < 64) LOADA((tt + 3) * 32);   // tile tt+3 -> RA
        COMPUTE(1);
        if (tt + 2 < 64) WRITEB(0);              // waits only RB's loads
        __syncthreads();
    }

    const int cb = L & 15;
    #pragma unroll
    for (int rt = 0; rt < 2; ++rt) {
        const int rloc = wr + rt * 16 + ((L >> 4) << 2);
        const int hb = (rloc < 64) ? hb0 : hb1;   // wave-uniform
        #pragma unroll
        for (int r = 0; r < 4; ++r) {
            const int q = (rloc + r) & 63;
            const float inv = 1.f / lsum[hb * 64 + q];
            #pragma unroll
            for (int nt = 0; nt < 3; ++nt) {
                f16 h, l; split(acc[rt][nt][r] * inv, h, l);
                const long o = ((long)hb * 64 + q) * 1536 + ct * 96 + wc + nt * 16 + cb;
                Uh[o] = h; Ul[o] = l;
            }
        }
    }
}

// ---------------------------------------------------------------------------
// f32 [K,N] -> transposed f16 pair [N,K]
__global__ void k_castTpair(const float* __restrict__ s, f16* __restrict__ dh,
                            f16* __restrict__ dl, int K, int Nn)
{
    const long i = (long)blockIdx.x * 256 + threadIdx.x;
    if (i >= (long)K * Nn) return;
    const int k = (int)(i / Nn), n = (int)(i - (long)k * Nn);
    f16 h, l; split(s[i], h, l);
    dh[(long)n * K + k] = h;
    dl[(long)n * K + k] = l;
}

// normb pair = f16pair( sqrt(sum_f pre^2) + EPS ).  Layout [tok*1536 + f*512 + c]
// (works for both kv_pre [NT toks] and resi_p [512 toks]).
__global__ void k_norm(const f16* __restrict__ kh, const f16* __restrict__ kl,
                       f16* __restrict__ nh, f16* __restrict__ nl)
{
    const long i = (long)blockIdx.x * 256 + threadIdx.x;
    const int tk = (int)(i >> 9), c = (int)(i & 511);
    const long base = (long)tk * 1536 + c;
    const float a = (float)kh[base]        + (float)kl[base];
    const float b = (float)kh[base + 512]  + (float)kl[base + 512];
    const float cc = (float)kh[base + 1024] + (float)kl[base + 1024];
    f16 h, l; split(sqrtf(a * a + b * b + cc * cc) + EPS, h, l);
    nh[i] = h; nl[i] = l;
}

// gate (in-place on kv pair) + kinv pair. One block per token.
__global__ __launch_bounds__(256) void k_gate(
    f16* __restrict__ kh, f16* __restrict__ kl, const float* __restrict__ g,
    f16* __restrict__ kih, f16* __restrict__ kil)
{
    __shared__ float red[3][4];
    const int t = threadIdx.x;
    const int tk = blockIdx.x;
    float kv[2][3];
    float ps0 = 0.f, ps1 = 0.f, ps2 = 0.f;
    #pragma unroll
    for (int j = 0; j < 2; ++j) {
        const int c = t + j * 256;
        const long base = (long)tk * 1536 + c;
        const float k0 = (float)kh[base]        + (float)kl[base];
        const float k1 = (float)kh[base + 512]  + (float)kl[base + 512];
        const float k2 = (float)kh[base + 1024] + (float)kl[base + 1024];
        const float nr = sqrtf(k0 * k0 + k1 * k1 + k2 * k2);
        const float gv = g[(long)tk * 512 + c];
        const float s = (nr <= EPS) ? 1.f : gv / (nr + EPS);
        kv[j][0] = k0 * s; kv[j][1] = k1 * s; kv[j][2] = k2 * s;
        f16 h, l;
        split(kv[j][0], h, l); kh[base] = h;        kl[base] = l;
        split(kv[j][1], h, l); kh[base + 512] = h;  kl[base + 512] = l;
        split(kv[j][2], h, l); kh[base + 1024] = h; kl[base + 1024] = l;
        ps0 += kv[j][0]; ps1 += kv[j][1]; ps2 += kv[j][2];
    }
    for (int off = 32; off; off >>= 1) {
        ps0 += __shfl_down(ps0, off);
        ps1 += __shfl_down(ps1, off);
        ps2 += __shfl_down(ps2, off);
    }
    if ((t & 63) == 0) { red[0][t >> 6] = ps0; red[1][t >> 6] = ps1; red[2][t >> 6] = ps2; }
    __syncthreads();
    const float m0 = (red[0][0] + red[0][1] + red[0][2] + red[0][3]) * (1.f / 512.f);
    const float m1 = (red[1][0] + red[1][1] + red[1][2] + red[1][3]) * (1.f / 512.f);
    const float m2 = (red[2][0] + red[2][1] + red[2][2] + red[2][3]) * (1.f / 512.f);
    #pragma unroll
    for (int j = 0; j < 2; ++j) {
        const int c = t + j * 256;
        f16 h, l; split(kv[j][0] * m0 + kv[j][1] * m1 + kv[j][2] * m2, h, l);
        kih[(long)tk * 512 + c] = h;
        kil[(long)tk * 512 + c] = l;
    }
}

// gate2: out[(tk,f,c)] = resi_p * (g2/(norm+EPS)), fp32 store. One block/token.
__global__ __launch_bounds__(256) void k_gate2(
    const f16* __restrict__ rph, const f16* __restrict__ rpl,
    const float* __restrict__ g2, float* __restrict__ out)
{
    const int t = threadIdx.x;
    const int tk = blockIdx.x;
    #pragma unroll
    for (int j = 0; j < 2; ++j) {
        const int c = t + j * 256;
        const long base = (long)tk * 1536 + c;
        const float r0 = (float)rph[base]        + (float)rpl[base];
        const float r1 = (float)rph[base + 512]  + (float)rpl[base + 512];
        const float r2 = (float)rph[base + 1024] + (float)rpl[base + 1024];
        const float nr = sqrtf(r0 * r0 + r1 * r1 + r2 * r2);
        const float gv = g2[(long)tk * 512 + c];
        const float s = (nr <= EPS) ? 1.f : gv / (nr + EPS);
        out[base]        = r0 * s;
        out[base + 512]  = r1 * s;
        out[base + 1024] = r2 * s;
    }
}

// ---------------------------------------------------------------------------
// q = LN(lq @ wq) per head (fp32 VALU, tiny), output f16 pair [h][qi][64].
__global__ __launch_bounds__(256) void k_qproj(
    const float* __restrict__ lq, const float* __restrict__ wq,
    const float* __restrict__ lns, const float* __restrict__ lnb,
    f16* __restrict__ qh, f16* __restrict__ ql)
{
    __shared__ float cs[QK];
    const int t = threadIdx.x;
    const int qi = blockIdx.x;
    const float* cp = lq + (long)qi * QK;
    for (int i = t; i < QK; i += 256) cs[i] = cp[i];
    __syncthreads();

    float a0 = 0, a1 = 0;
    #pragma unroll 4
    for (int d = 0; d < QK; ++d) {
        const float c = cs[d];
        a0 += c * wq[d * QK + t];
        a1 += c * wq[d * QK + t + 256];
    }
    float s0 = a0, q0 = a0 * a0, s1 = a1, q1 = a1 * a1;
    for (int off = 32; off; off >>= 1) {
        s0 += __shfl_down(s0, off); q0 += __shfl_down(q0, off);
        s1 += __shfl_down(s1, off); q1 += __shfl_down(q1, off);
    }
    s0 = __shfl(s0, 0); q0 = __shfl(q0, 0);
    s1 = __shfl(s1, 0); q1 = __shfl(q1, 0);
    const float mean0 = s0 * (1.f / 64.f), var0 = q0 * (1.f / 64.f) - mean0 * mean0;
    const float mean1 = s1 * (1.f / 64.f), var1 = q1 * (1.f / 64.f) - mean1 * mean1;
    const int e = t & 63;
    const float sc = lns[e], bi = lnb[e];
    const float r0 = (a0 - mean0) * rsqrtf(var0 + LNE) * sc + bi;
    const float r1 = (a1 - mean1) * rsqrtf(var1 + LNE) * sc + bi;
    const int h0 = t >> 6, h1 = h0 + 4;
    f16 h, l;
    split(r0, h, l);
    qh[((long)h0 * Qq + qi) * DH + e] = h;
    ql[((long)h0 * Qq + qi) * DH + e] = l;
    split(r1, h, l);
    qh[((long)h1 * Qq + qi) * DH + e] = h;
    ql[((long)h1 * Qq + qi) * DH + e] = l;
}

// ---------------------------------------------------------------------------
extern "C" void kernel_launch(void* const* d_in, const int* in_sizes, int n_in,
                              void* d_out, int out_size, void* d_ws, size_t ws_size,
                              hipStream_t stream)
{
    const float* x    = (const float*)d_in[0];
    const float* lq   = (const float*)d_in[1];
    const float* w_kv = (const float*)d_in[2];
    const float* w1a  = (const float*)d_in[3];
    const float* b1a  = (const float*)d_in[4];
    const float* w1b  = (const float*)d_in[5];
    const float* b1b  = (const float*)d_in[6];
    const float* wq   = (const float*)d_in[7];
    const float* wk   = (const float*)d_in[8];
    const float* wv   = (const float*)d_in[9];
    const float* lqs  = (const float*)d_in[10];
    const float* lqb  = (const float*)d_in[11];
    const float* lks  = (const float*)d_in[12];
    const float* lkb  = (const float*)d_in[13];
    const float* wo   = (const float*)d_in[14];
    const float* w2a  = (const float*)d_in[15];
    const float* b2a  = (const float*)d_in[16];
    const float* w2b  = (const float*)d_in[17];
    const float* b2b  = (const float*)d_in[18];

    char* ws = (char*)d_ws;
    // Layout (191.5 MB, lifetime-aliased):
    //  W  [0, 3670016): stage-1 weight pairs
    //  S  [3670016, 3817472): qhp | qlp | lsum
    //  W2 [3817472, 5914624): wo/w2a/w2b pairs (stage-2 weights)
    //  LP [5914624, 6045696): lsum partials (8 x 4096 f32)
    //  A1 [6946816, 40501248): normb pair -> kinv pair -> attn pair -> stage-2 bufs
    //  A2 [40501248, 57278464): hb pair -> resiT f32
    //  B  [57278464, 157941760): kv pair (pre -> gated in-place)
    //  D  [157941760, 191496192): g f32 -> k pair -> U pair
    f16* wkvTh = (f16*)(ws + 0);
    f16* wkvTl = (f16*)(ws + 262144);
    f16* w1aTh = (f16*)(ws + 524288);
    f16* w1aTl = (f16*)(ws + 786432);
    f16* w1bTh = (f16*)(ws + 1048576);
    f16* w1bTl = (f16*)(ws + 1310720);
    f16* wkTh  = (f16*)(ws + 1572864);
    f16* wkTl  = (f16*)(ws + 2097152);
    f16* wvTh  = (f16*)(ws + 2621440);
    f16* wvTl  = (f16*)(ws + 3145728);
    f16*   qhp   = (f16*)(ws + 3670016);
    f16*   qlp   = (f16*)(ws + 3735552);
    float* lsum  = (float*)(ws + 3801088);
    f16* woTh  = (f16*)(ws + 3817472);
    f16* woTl  = (f16*)(ws + 4341760);
    f16* w2aTh = (f16*)(ws + 4866048);
    f16* w2aTl = (f16*)(ws + 5128192);
    f16* w2bTh = (f16*)(ws + 5390336);
    f16* w2bTl = (f16*)(ws + 5652480);
    float* lsum_part = (float*)(ws + 5914624);  // 131072 B
    f16* nh    = (f16*)(ws + 6946816);
    f16* nl    = (f16*)(ws + 23724032);
    f16* kih   = nh;
    f16* kil   = nl;
    f16* ath   = (f16*)(ws + 6946816);
    f16* atl   = (f16*)(ws + 23724032);
    // stage-2 buffers (A1 region; attn dead after step 10)
    f16*   rph  = (f16*)(ws + 6946816);    // 1,572,864
    f16*   rpl  = (f16*)(ws + 8519680);    // 1,572,864
    f16*   n2h  = (f16*)(ws + 10092544);   //   524,288
    f16*   n2l  = (f16*)(ws + 10616832);   //   524,288
    f16*   h2h  = (f16*)(ws + 11141120);   //   262,144
    f16*   h2l  = (f16*)(ws + 11403264);   //   262,144
    float* g2   = (float*)(ws + 11665408); // 1,048,576
    f16* hbh   = (f16*)(ws + 40501248);
    f16* hbl   = (f16*)(ws + 48889856);
    float* resiT = (float*)(ws + 40501248); // aliases hb (dead after step 5)
    f16* kvh   = (f16*)(ws + 57278464);
    f16* kvl   = (f16*)(ws + 107610112);
    float* g    = (float*)(ws + 157941760);
    f16* khb   = (f16*)(ws + 157941760);
    f16* klb   = (f16*)(ws + 174718976);
    f16* Uh    = (f16*)(ws + 157941760);
    f16* Ul    = (f16*)(ws + 170524672);
    float* out  = (float*)d_out;

    // 1. weight casts (transposed pairs)
    k_castTpair<<<512,  256, 0, stream>>>(w_kv, wkvTh, wkvTl, Dd, QK);
    k_castTpair<<<512,  256, 0, stream>>>(w1a,  w1aTh, w1aTl, QK, 256);
    k_castTpair<<<512,  256, 0, stream>>>(w1b,  w1bTh, w1bTl, 256, QK);
    k_castTpair<<<1024, 256, 0, stream>>>(wk,   wkTh,  wkTl,  QK, QK);
    k_castTpair<<<1024, 256, 0, stream>>>(wv,   wvTh,  wvTl,  QK, QK);
    k_castTpair<<<1024, 256, 0, stream>>>(wo,   woTh,  woTl,  Vd, Vd);
    k_castTpair<<<512,  256, 0, stream>>>(w2a,  w2aTh, w2aTl, Vd, 256);
    k_castTpair<<<512,  256, 0, stream>>>(w2b,  w2bTh, w2bTl, 256, Vd);

    // 2. kv_pre = x @ w_kv -> kv pair (dist-2 pipelined, BK=32, swizzled)
    k_kv2<<<1536, 512, 0, stream>>>(x, wkvTh, wkvTl, kvh, kvl);
    // 3. norm
    k_norm<<<32768, 256, 0, stream>>>(kvh, kvl, nh, nl);
    // 4. h = leaky(norm @ w1a + b1a) -> hb pair
    k_gemm3<0, 1><<<dim3(128, 4), 256, 0, stream>>>(
        nullptr, nh, nl, w1aTh, w1aTl, 256, QK, hbh, hbl, b1a, nullptr);
    // 5. g = h @ w1b + b1b -> f32
    k_gemm3<0, 2><<<dim3(128, 8), 256, 0, stream>>>(
        nullptr, hbh, hbl, w1bTh, w1bTl, QK, 256, g, nullptr, b1b, nullptr);
    // 6. gate in-place + kinv pair
    k_gate<<<NT, 256, 0, stream>>>(kvh, kvl, g, kih, kil);
    // 7. k = LN(kinv @ wk) -> k pair [h][tok][64]
    k_gemm3<0, 3><<<dim3(128, 8), 256, 0, stream>>>(
        nullptr, kih, kil, wkTh, wkTl, QK, QK, khb, klb, lks, lkb);
    // 8. q -> pair
    k_qproj<<<Qq, 256, 0, stream>>>(lq, wq, lqs, lqb, qhp, qlp);
    // 9. attn: MFMA QK^T + exp + partial rowsum (512 blocks = 64 hb x 8 parts)
    k_attn_mfma<<<512, 256, 0, stream>>>(qhp, qlp, khb, klb, ath, atl, lsum_part);
    // 9b. reduce partial rowsums
    k_lsum_reduce<<<16, 256, 0, stream>>>(lsum_part, lsum);
    // 10. U = (attn @ kv) / lsum -> U pair (dist-2 reg pipeline, swizzled LDS)
    k_gemm3T<<<512, 512, 0, stream>>>(ath, atl, kvh, kvl, lsum, Uh, Ul);
    // 11. resi = U @ wv -> resiT f32 [(b,q,f)][512]
    k_gemm3<0, 5><<<dim3(12, 8), 256, 0, stream>>>(
        nullptr, Uh, Ul, wvTh, wvTl, 64, QK, resiT, nullptr, nullptr, nullptr);
    // 12a. resi_p = resiT @ w_out -> pair  [1536,512]
    k_gemm3<1, 0><<<dim3(12, 8), 256, 0, stream>>>(
        resiT, nullptr, nullptr, woTh, woTl, Vd, Vd, rph, rpl, nullptr, nullptr);
    // 12b. norm2 over f (512 tokens)
    k_norm<<<1024, 256, 0, stream>>>(rph, rpl, n2h, n2l);
    // 12c. h2 = leaky(norm2 @ w2a + b2a) -> pair [512,256]
    k_gemm3<0, 1><<<dim3(4, 4), 256, 0, stream>>>(
        nullptr, n2h, n2l, w2aTh, w2aTl, 256, Vd, h2h, h2l, b2a, nullptr);
    // 12d. g2 = h2 @ w2b + b2b -> f32 [512,512]
    k_gemm3<0, 2><<<dim3(4, 8), 256, 0, stream>>>(
        nullptr, h2h, h2l, w2bTh, w2bTl, Vd, 256, g2, nullptr, b2b, nullptr);
    // 12e. out = resi_p * g2/(norm+EPS), fp32
    k_gate2<<<B * Qq, 256, 0, stream>>>(rph, rpl, g2, out);
}